// Round 2
// baseline (256.636 us; speedup 1.0000x reference)
//
#include <hip/hip_runtime.h>
#include <math.h>

#define GN 2048
#define GD_IN 128
#define GD_OUT 64

typedef float f4 __attribute__((ext_vector_type(4)));

// Kernel 1: h = X @ W^T  [N, D_OUT]; s_i = h @ a[:64]; s_j = h @ a[64:]
__global__ __launch_bounds__(64) void gat_h_kernel(
    const float* __restrict__ x,   // [N, 128]
    const float* __restrict__ W,   // [64, 128]
    const float* __restrict__ a,   // [128]
    float* __restrict__ h,         // [N, 64]
    float* __restrict__ s_i,       // [N]
    float* __restrict__ s_j) {     // [N]
    __shared__ float wl[GD_OUT * (GD_IN + 1)];  // +1 pad -> conflict-free
    __shared__ float xl[GD_IN];
    const int i = blockIdx.x;
    const int t = threadIdx.x;  // 0..63

    for (int idx = t; idx < GD_OUT * GD_IN; idx += 64) {
        int o = idx >> 7, k = idx & 127;
        wl[o * (GD_IN + 1) + k] = W[idx];
    }
    xl[t]      = x[i * GD_IN + t];
    xl[t + 64] = x[i * GD_IN + t + 64];
    __syncthreads();

    float acc = 0.f;
    const float* wr = &wl[t * (GD_IN + 1)];
    #pragma unroll
    for (int k = 0; k < GD_IN; ++k) acc = fmaf(xl[k], wr[k], acc);
    h[i * GD_OUT + t] = acc;

    float p1 = acc * a[t];
    float p2 = acc * a[GD_OUT + t];
    #pragma unroll
    for (int off = 32; off; off >>= 1) {
        p1 += __shfl_down(p1, off);
        p2 += __shfl_down(p2, off);
    }
    if (t == 0) { s_i[i] = p1; s_j[i] = p2; }
}

// Kernel 2: per-row softmax statistics -> rowp[i] = (s_i, rmax, 1/sum, 0)
__global__ __launch_bounds__(256) void gat_rowstat_kernel(
    const int* __restrict__ mask,  // [N, N]
    const float* __restrict__ s_i, // [N]
    const float* __restrict__ s_j, // [N]
    f4* __restrict__ rowp) {       // [N]
    __shared__ float sc[GN];
    __shared__ float red[4];
    const int i = blockIdx.x;
    const int t = threadIdx.x;  // 0..255
    const float si = s_i[i];

    float lmax = -INFINITY;
    for (int j = t; j < GN; j += 256) {
        float z = si + s_j[j];
        float s = z > 0.f ? z : 0.01f * z;
        s = mask[(size_t)i * GN + j] ? s : -INFINITY;
        sc[j] = s;
        lmax = fmaxf(lmax, s);
    }
    #pragma unroll
    for (int off = 32; off; off >>= 1) lmax = fmaxf(lmax, __shfl_down(lmax, off));
    if ((t & 63) == 0) red[t >> 6] = lmax;
    __syncthreads();
    float rmax = fmaxf(fmaxf(red[0], red[1]), fmaxf(red[2], red[3]));
    if (rmax == -INFINITY) rmax = 0.f;  // all-invalid row -> sum 0 -> inv 0

    float lsum = 0.f;
    for (int j = t; j < GN; j += 256) lsum += __expf(sc[j] - rmax);
    #pragma unroll
    for (int off = 32; off; off >>= 1) lsum += __shfl_down(lsum, off);
    __syncthreads();   // all done reading red(max)
    if ((t & 63) == 0) red[t >> 6] = lsum;
    __syncthreads();
    if (t == 0) {
        float ssum = red[0] + red[1] + red[2] + red[3];
        f4 rp;
        rp.x = si;
        rp.y = rmax;
        rp.z = ssum > 0.f ? 1.f / ssum : 0.f;
        rp.w = 0.f;
        rowp[i] = rp;
    }
}

// Kernel 3: pure streaming writer. Thread's (j, o4) fixed for all iterations
// -> h fragment and s_j are loop-invariant registers. Per iter: uniform rowp
// load + mask dword + ~10 VALU + exp + one NT dwordx4 store.
__global__ __launch_bounds__(256) void gat_write_kernel(
    const int* __restrict__ mask,  // [N, N]
    const float* __restrict__ h,   // [N, 64]
    const float* __restrict__ s_j, // [N]
    const f4* __restrict__ rowp,   // [N]
    f4* __restrict__ out4) {       // [N*N*16]
    const int t = blockIdx.x * 256 + threadIdx.x;  // 0..524287
    const int o4 = t & 15;
    const int j  = (t >> 4) & (GN - 1);
    const f4 hv = reinterpret_cast<const f4*>(h)[(j << 4) | o4];
    const float sj = s_j[j];

    size_t f = (size_t)t;
    #pragma unroll 4
    for (int it = 0; it < (GN * GN * 16) / (2048 * 256); ++it, f += 2048 * 256) {
        const int i = (int)(f >> 15);         // uniform within block
        const f4 rp = rowp[i];                // (si, rmax, inv, 0)
        const int m = mask[f >> 4];
        float z = rp.x + sj;
        float s = z > 0.f ? z : 0.01f * z;
        float e = __expf(s - rp.y) * rp.z;
        float al = m ? e : 0.f;
        __builtin_nontemporal_store(hv * al, &out4[f]);
    }
}

extern "C" void kernel_launch(void* const* d_in, const int* in_sizes, int n_in,
                              void* d_out, int out_size, void* d_ws, size_t ws_size,
                              hipStream_t stream) {
    const float* x    = (const float*)d_in[0];   // [2048, 128]
    const int*   mask = (const int*)d_in[1];     // [2048, 2048]
    const float* W    = (const float*)d_in[2];   // [64, 128]
    const float* a    = (const float*)d_in[3];   // [128]
    float* out = (float*)d_out;                  // [2048, 2048, 64]

    float* ws  = (float*)d_ws;
    float* h   = ws;                   // 131072 floats
    float* s_i = ws + GN * GD_OUT;     // 2048
    float* s_j = s_i + GN;             // 2048
    f4*    rowp = (f4*)(s_j + GN);     // 2048 f4 (16B-aligned: 540672 % 16 == 0)

    gat_h_kernel<<<GN, 64, 0, stream>>>(x, W, a, h, s_i, s_j);
    gat_rowstat_kernel<<<GN, 256, 0, stream>>>(mask, s_i, s_j, rowp);
    gat_write_kernel<<<2048, 256, 0, stream>>>(mask, h, s_j, rowp, (f4*)out);
}

// Round 3
// 214.571 us; speedup vs baseline: 1.1960x; 1.1960x over previous
//
#include <hip/hip_runtime.h>
#include <math.h>

#define GN 2048
#define GD_IN 128
#define GD_OUT 64

typedef float f4 __attribute__((ext_vector_type(4)));

// Kernel 1: h = X @ W^T  [N, D_OUT]; s_i = h @ a[:64]; s_j = h @ a[64:]
__global__ __launch_bounds__(64) void gat_h_kernel(
    const float* __restrict__ x,   // [N, 128]
    const float* __restrict__ W,   // [64, 128]
    const float* __restrict__ a,   // [128]
    float* __restrict__ h,         // [N, 64]
    float* __restrict__ s_i,       // [N]
    float* __restrict__ s_j) {     // [N]
    __shared__ float wl[GD_OUT * (GD_IN + 1)];  // +1 pad -> conflict-free
    __shared__ float xl[GD_IN];
    const int i = blockIdx.x;
    const int t = threadIdx.x;  // 0..63

    for (int idx = t; idx < GD_OUT * GD_IN; idx += 64) {
        int o = idx >> 7, k = idx & 127;
        wl[o * (GD_IN + 1) + k] = W[idx];
    }
    xl[t]      = x[i * GD_IN + t];
    xl[t + 64] = x[i * GD_IN + t + 64];
    __syncthreads();

    float acc = 0.f;
    const float* wr = &wl[t * (GD_IN + 1)];
    #pragma unroll
    for (int k = 0; k < GD_IN; ++k) acc = fmaf(xl[k], wr[k], acc);
    h[i * GD_OUT + t] = acc;

    float p1 = acc * a[t];
    float p2 = acc * a[GD_OUT + t];
    #pragma unroll
    for (int off = 32; off; off >>= 1) {
        p1 += __shfl_down(p1, off);
        p2 += __shfl_down(p2, off);
    }
    if (t == 0) { s_i[i] = p1; s_j[i] = p2; }
}

// Kernel 2 (fused): one block per row i. Masked leaky-relu scores -> softmax
// -> prescaled alpha in LDS -> stream messages[i,j,:] = alpha[i,j] * h[j,:].
__global__ __launch_bounds__(256) void gat_msg_kernel(
    const int* __restrict__ mask,  // [N, N] int32 (0/1)
    const float* __restrict__ h,   // [N, 64]
    const float* __restrict__ s_i, // [N]
    const float* __restrict__ s_j, // [N]
    float* __restrict__ out) {     // [N, N, 64]
    __shared__ float sc[GN];   // scores -> exp -> alpha
    __shared__ float red[4];
    const int i = blockIdx.x;
    const int t = threadIdx.x;  // 0..255
    const float si = s_i[i];

    // Pass 1: masked leaky-relu scores + local max
    float lmax = -INFINITY;
    for (int j = t; j < GN; j += 256) {
        float z = si + s_j[j];
        float s = z > 0.f ? z : 0.01f * z;
        s = mask[(size_t)i * GN + j] ? s : -INFINITY;
        sc[j] = s;
        lmax = fmaxf(lmax, s);
    }
    #pragma unroll
    for (int off = 32; off; off >>= 1) lmax = fmaxf(lmax, __shfl_down(lmax, off));
    if ((t & 63) == 0) red[t >> 6] = lmax;
    __syncthreads();
    float rmax = fmaxf(fmaxf(red[0], red[1]), fmaxf(red[2], red[3]));
    if (rmax == -INFINITY) rmax = 0.f;  // all-invalid row -> alpha row = 0

    // Pass 2: exp + local sum
    float lsum = 0.f;
    for (int j = t; j < GN; j += 256) {
        float e = __expf(sc[j] - rmax);   // exp(-inf) == 0 for unmasked
        sc[j] = e;
        lsum += e;
    }
    #pragma unroll
    for (int off = 32; off; off >>= 1) lsum += __shfl_down(lsum, off);
    __syncthreads();
    if ((t & 63) == 0) red[t >> 6] = lsum;
    __syncthreads();
    const float ssum = red[0] + red[1] + red[2] + red[3];
    const float inv = ssum > 0.f ? 1.f / ssum : 0.f;

    // Pass 3: prescale alpha in place (each thread owns its sc slots)
    for (int j = t; j < GN; j += 256) sc[j] *= inv;
    __syncthreads();

    // Write phase: 16 j's x 16 float4-lanes per iteration, PLAIN stores.
    const f4* __restrict__ h4 = reinterpret_cast<const f4*>(h);
    f4* __restrict__ out4 = reinterpret_cast<f4*>(out) + (size_t)i * GN * (GD_OUT / 4);
    const int jl = t >> 4;   // 0..15
    const int o4 = t & 15;   // 0..15
    #pragma unroll 4
    for (int jb = 0; jb < GN; jb += 16) {
        int j = jb + jl;
        float al = sc[j];                // LDS broadcast (16 lanes share j)
        f4 hv = h4[j * (GD_OUT / 4) + o4];
        out4[(size_t)j * (GD_OUT / 4) + o4] = hv * al;
    }
}

extern "C" void kernel_launch(void* const* d_in, const int* in_sizes, int n_in,
                              void* d_out, int out_size, void* d_ws, size_t ws_size,
                              hipStream_t stream) {
    const float* x    = (const float*)d_in[0];   // [2048, 128]
    const int*   mask = (const int*)d_in[1];     // [2048, 2048]
    const float* W    = (const float*)d_in[2];   // [64, 128]
    const float* a    = (const float*)d_in[3];   // [128]
    float* out = (float*)d_out;                  // [2048, 2048, 64]

    float* ws  = (float*)d_ws;
    float* h   = ws;                 // 2048*64 floats
    float* s_i = ws + GN * GD_OUT;   // 2048 floats
    float* s_j = s_i + GN;           // 2048 floats

    gat_h_kernel<<<GN, 64, 0, stream>>>(x, W, a, h, s_i, s_j);
    gat_msg_kernel<<<GN, 256, 0, stream>>>(mask, h, s_i, s_j, out);
}